// Round 20
// baseline (88.260 us; speedup 1.0000x reference)
//
#include <hip/hip_runtime.h>
#include <hip/hip_bf16.h>
#include <math.h>

#define SCALE  0.17677669529663687f            // 1/sqrt(32)
#define QSCALE 0.25501817444361255f            // SCALE * log2(e)  (exp2 domain)

#if __has_builtin(__builtin_amdgcn_exp2f)
#define EXP2(x) __builtin_amdgcn_exp2f(x)
#else
#define EXP2(x) exp2f(x)
#endif

typedef __attribute__((ext_vector_type(8))) short bf16x8;
typedef __attribute__((ext_vector_type(4))) float f32x4;
typedef unsigned int u32;
typedef unsigned short u16;

#define MFMA16(a, b, c) __builtin_amdgcn_mfma_f32_16x16x32_bf16(a, b, c, 0, 0, 0)

__device__ inline u32 bf16rne(float x) {
    u32 u = __float_as_uint(x);
    return (u + 0x7FFFu + ((u >> 16) & 1u)) >> 16;
}
__device__ inline float bf16tof(u32 h) { return __uint_as_float(h << 16); }
// pack 2 floats -> 2 bf16 (RNE) in one u32 (lo = a)
__device__ inline u32 pkbf2(float a, float b) {
    union { __hip_bfloat162 h; u32 u; } cv;
    cv.h = __float22bfloat162_rn(make_float2(a, b));
    return cv.u;
}
// byte addr within a tile of 128-byte rows, XOR-swizzled (G4 / T2)
__device__ inline int swzb(int row, int b) { return row * 128 + (b ^ ((row & 7) << 4)); }

typedef __attribute__((address_space(1))) const u32 gu32;
typedef __attribute__((address_space(3))) u32 lu32;
#define GL16(g, l) __builtin_amdgcn_global_load_lds((gu32*)(const void*)(g), (lu32*)(void*)(l), 16, 0, 0)

// ---------------------------------------------------------------------------
// Convert + transpose weights: g<5: W[768][256] -> Wt[g][256][768] HI only
// (proj is uniform 2-term); g==5: Wo -> Wot hi+lo.  grid (12, 4, 6).
// ---------------------------------------------------------------------------
__global__ __launch_bounds__(256) void conv_w(
    const float* __restrict__ W0, const float* __restrict__ W1,
    const float* __restrict__ W2, const float* __restrict__ W3,
    const float* __restrict__ W4, const float* __restrict__ Wo,
    u16* __restrict__ W5t_hi, u16* __restrict__ W5t_lo,
    u16* __restrict__ Wot_hi, u16* __restrict__ Wot_lo)
{
    const int g = blockIdx.z;
    const float* W; int K; u16 *dh, *dl;
    switch (g) {
        case 0: W = W0; K = 768; dh = W5t_hi;              dl = nullptr;  break;
        case 1: W = W1; K = 768; dh = W5t_hi + 196608;     dl = nullptr;  break;
        case 2: W = W2; K = 768; dh = W5t_hi + 2 * 196608; dl = nullptr;  break;
        case 3: W = W3; K = 768; dh = W5t_hi + 3 * 196608; dl = nullptr;  break;
        case 4: W = W4; K = 768; dh = W5t_hi + 4 * 196608; dl = nullptr;  break;
        default: W = Wo; K = 256; dh = Wot_hi; dl = Wot_lo; break;
    }
    (void)W5t_lo;
    const int k0 = blockIdx.x * 64, n0 = blockIdx.y * 64;
    if (k0 >= K) return;
    __shared__ float T[64][65];
    const int t = threadIdx.x;
    #pragma unroll
    for (int rep = 0; rep < 4; ++rep) {
        int kr = rep * 16 + (t >> 4);
        int nc = (t & 15) * 4;
        float4 f = *(const float4*)&W[(size_t)(k0 + kr) * 256 + n0 + nc];
        T[kr][nc] = f.x; T[kr][nc + 1] = f.y; T[kr][nc + 2] = f.z; T[kr][nc + 3] = f.w;
    }
    __syncthreads();
    #pragma unroll
    for (int rep = 0; rep < 4; ++rep) {
        int idx = rep * 256 + t;
        int n = idx >> 4, kq = (idx & 15) * 4;
        float v0 = T[kq + 0][n], v1 = T[kq + 1][n], v2 = T[kq + 2][n], v3 = T[kq + 3][n];
        u32 h0 = bf16rne(v0), h1 = bf16rne(v1), h2 = bf16rne(v2), h3 = bf16rne(v3);
        ushort4 hv = {(u16)h0, (u16)h1, (u16)h2, (u16)h3};
        size_t o = (size_t)(n0 + n) * K + k0 + kq;
        *(ushort4*)&dh[o] = hv;
        if (dl) {
            ushort4 lv = {(u16)bf16rne(v0 - bf16tof(h0)), (u16)bf16rne(v1 - bf16tof(h1)),
                          (u16)bf16rne(v2 - bf16tof(h2)), (u16)bf16rne(v3 - bf16tof(h3))};
            *(ushort4*)&dl[o] = lv;
        }
    }
}

// ---------------------------------------------------------------------------
// Fused projection v4: BN=64 for occupancy. Uniform 2-term ((xh+xl)*wh),
// W double-buffered (one barrier per k-step), X wave-private reg-staged
// (4 waves x 16 rows = 64: privacy preserved). grid 1280 1-D, XCD decode:
// v=(i&7)*160+(i>>3); unit=v%20; g=unit>>2; quarter=unit&3; bm=(v/20)*64.
// LDS: XH 8K + XL 8K + W 2x8K = 32 KB -> 5 blocks/CU, grid = exactly 5/CU.
// ---------------------------------------------------------------------------
__global__ __launch_bounds__(256, 5) void proj_fused(
    const float* __restrict__ A, const float* __restrict__ Bm,
    const u16* __restrict__ W5t_hi,
    const float* __restrict__ b0, const float* __restrict__ b1,
    const float* __restrict__ b2, const float* __restrict__ b3,
    const float* __restrict__ b4,
    u16* __restrict__ Qpk_hi, u16* __restrict__ Qpk_lo,
    u16* __restrict__ Kpk_hi, u16* __restrict__ Vt_hi)
{
    __shared__ u16 XH[64 * 64], XL[64 * 64];
    __shared__ u16 WB[2][64 * 64];

    const int t = threadIdx.x, w = t >> 6, l = t & 63;
    const int l15 = l & 15, lg = l >> 4;

    const int i = blockIdx.x;                  // 0..1279
    const int v = (i & 7) * 160 + (i >> 3);    // bijective (1280 = 8*160)
    const int unit = v % 20;
    const int g = unit >> 2;
    const int quarter = unit & 3;
    const int bm = (v / 20) * 64;

    const float* X = (g == 4) ? Bm : A;
    const u16* Wh = W5t_hi + (size_t)g * 196608 + (size_t)quarter * 49152;
    const float* bias;
    switch (g) {
        case 0: bias = b0; break;
        case 1: bias = b1; break;
        case 2: bias = b2; break;
        case 3: bias = b3; break;
        default: bias = b4; break;
    }
    const bool isq = (g == 0 || g == 3);

    const int lr = l >> 3;                                  // 0..7
    const int wswz = ((l & 7) * 16) ^ ((lr & 7) << 4);
    const u16* whp = Wh + (size_t)lr * 768 + (wswz >> 1);

    const int xr = t >> 2;
    const float* xp = X + (size_t)(bm + xr) * 768 + (t & 3) * 16;
    const int xb0 = swzb(xr, (t & 3) * 32);
    const int xb1 = swzb(xr, (t & 3) * 32 + 16);

    f32x4 acc[4];
    #pragma unroll
    for (int cg = 0; cg < 4; ++cg) acc[cg] = (f32x4){0.f, 0.f, 0.f, 0.f};

    float4 fc0, fc1, fc2, fc3;
    auto load_x = [&]() {
        fc0 = ((const float4*)xp)[0]; fc1 = ((const float4*)xp)[1];
        fc2 = ((const float4*)xp)[2]; fc3 = ((const float4*)xp)[3];
        xp += 64;
    };
    auto convert_x = [&]() {
        float va[16] = {fc0.x, fc0.y, fc0.z, fc0.w, fc1.x, fc1.y, fc1.z, fc1.w,
                        fc2.x, fc2.y, fc2.z, fc2.w, fc3.x, fc3.y, fc3.z, fc3.w};
        u32 hp[8], lp[8];
        #pragma unroll
        for (int jj = 0; jj < 8; ++jj) {
            float a = va[2 * jj], bq = va[2 * jj + 1];
            u32 hq = pkbf2(a, bq);
            hp[jj] = hq;
            lp[jj] = pkbf2(a - bf16tof(hq & 0xffffu), bq - bf16tof(hq >> 16));
        }
        uint4 u;
        u.x = hp[0]; u.y = hp[1]; u.z = hp[2]; u.w = hp[3];
        *(uint4*)((char*)XH + xb0) = u;
        u.x = hp[4]; u.y = hp[5]; u.z = hp[6]; u.w = hp[7];
        *(uint4*)((char*)XH + xb1) = u;
        u.x = lp[0]; u.y = lp[1]; u.z = lp[2]; u.w = lp[3];
        *(uint4*)((char*)XL + xb0) = u;
        u.x = lp[4]; u.y = lp[5]; u.z = lp[6]; u.w = lp[7];
        *(uint4*)((char*)XL + xb1) = u;
    };
    auto stage_w = [&](u16* buf) {
        #pragma unroll
        for (int j = 0; j < 2; ++j) {
            int c = w * 2 + j;
            GL16(whp + (size_t)c * 6144, &buf[c * 512]);
        }
        whp += 64;
    };

    // ---- prologue: X(0) regs -> LDS; W(0) -> buf0; X(1) regs ----
    load_x();
    stage_w(WB[0]);
    convert_x();
    load_x();

    for (int ks = 0; ks < 12; ++ks) {
        __syncthreads();   // W(ks) landed; waves done reading WB[(ks+1)&1]
        if (ks < 11) stage_w(WB[(ks + 1) & 1]);

        // ---- compute(ks): (xh + xl) * wh, rows w*16.., 64 cols ----
        const char* Wc = (const char*)WB[ks & 1];
        #pragma unroll
        for (int s = 0; s < 2; ++s) {
            int byo = s * 64 + lg * 16;
            bf16x8 ah = *(const bf16x8*)((const char*)XH + swzb(w * 16 + l15, byo));
            bf16x8 al = *(const bf16x8*)((const char*)XL + swzb(w * 16 + l15, byo));
            #pragma unroll
            for (int cg = 0; cg < 4; ++cg) {
                bf16x8 bh = *(const bf16x8*)(Wc + swzb(cg * 16 + l15, byo));
                acc[cg] = MFMA16(ah, bh, acc[cg]);
                acc[cg] = MFMA16(al, bh, acc[cg]);
            }
        }

        // ---- refill X (wave-private rows w*16..: in-order DS, no barrier) ----
        if (ks < 11) {
            convert_x();
            if (ks < 10) load_x();
        }
    }

    float biasv[4];
    #pragma unroll
    for (int cg = 0; cg < 4; ++cg) biasv[cg] = bias[quarter * 64 + cg * 16 + l15];

    if (g != 2) {
        u16* Dh = isq ? Qpk_hi : Kpk_hi;
        const int dofs = (g == 3 || g == 4) ? 32 : 0;
        #pragma unroll
        for (int cg = 0; cg < 4; ++cg) {
            int c = quarter * 64 + cg * 16 + l15;
            int h = c >> 5, d = (c & 31) + dofs;
            #pragma unroll
            for (int r = 0; r < 4; ++r) {
                int row = bm + w * 16 + lg * 4 + r;
                float y = acc[cg][r] + biasv[cg];
                if (isq) y *= QSCALE;       // exp2-domain logits
                u32 hb = bf16rne(y);
                size_t o = ((size_t)row * 8 + h) * 64 + d;
                Dh[o] = (u16)hb;
                if (isq) Qpk_lo[o] = (u16)bf16rne(y - bf16tof(hb));
            }
        }
    } else {
        // V: transpose [64 k][64 d] -> [64 d][64 k] via WB[0] (done with W)
        __syncthreads();
        #pragma unroll
        for (int cg = 0; cg < 4; ++cg) {
            int dl = cg * 16 + l15;            // 0..63 local
            #pragma unroll
            for (int r = 0; r < 4; ++r) {
                int kl = w * 16 + lg * 4 + r;  // 0..63
                float y = acc[cg][r] + biasv[cg];
                int byo = (2 * kl) ^ ((dl & 7) << 4);
                *(u16*)((char*)WB[0] + dl * 128 + byo) = (u16)bf16rne(y);
            }
        }
        __syncthreads();
        const int bb = bm >> 11, kb = bm & 2047;
        #pragma unroll
        for (int rep = 0; rep < 4; ++rep) {
            int idx = rep * 256 + t;           // 0..1023
            int dl = idx >> 4;                 // 0..63 local
            int kq = idx & 15;                 // 4-k chunk
            int dg = quarter * 64 + dl;
            int h = dg >> 5, d = dg & 31;
            int byo = (8 * kq) ^ ((dl & 7) << 4);
            ushort4 hv = *(const ushort4*)((const char*)WB[0] + dl * 128 + byo);
            size_t o = (((size_t)bb * 8 + h) * 32 + d) * 2048 + kb + kq * 4;
            *(ushort4*)&Vt_hi[o] = hv;
        }
    }
}

// ---------------------------------------------------------------------------
// MFMA flash attention v8 (anchor, unchanged): 2-phase dbuf prefetch,
// k-split 2, XCD swizzle, swapped QK^T, exp2 domain, defer-max. No setprio.
// grid 1024. LDS = 32 KB -> 4 blocks/CU.
// ---------------------------------------------------------------------------
__global__ __launch_bounds__(256, 4) void attn_mfma8(
    const u16* __restrict__ Qpk_hi, const u16* __restrict__ Qpk_lo,
    const u16* __restrict__ Kpk_hi, const u16* __restrict__ Vt_hi,
    float* __restrict__ Opart, float* __restrict__ Oml)
{
    __shared__ u16 KH[2][64 * 64], VH[2][32 * 64];
    __shared__ u16 PH[4][16 * 64];

    const int t = threadIdx.x, w = t >> 6, l = t & 63;
    const int l15 = l & 15, lg = l >> 4;

    // XCD-aware decode (T1): i%8 = XCD; 128 consecutive v per XCD.
    const int i = blockIdx.x;                  // 0..1023
    const int v = (i & 7) * 128 + (i >> 3);    // bijective (1024 % 8 == 0)
    const int panel = v >> 5;                  // 0..31 = (h, b, ks)
    const int qb   = v & 31;                   // q-block within panel
    const int h = panel >> 2;
    const int z = panel & 3;
    const int b = z >> 1, ks = z & 1;
    const int q0 = qb * 64 + w * 16;
    const int base = b * 2048;

    // Q fragments (QSCALE pre-folded)
    bf16x8 qh[2], ql[2];
    {
        size_t ro = ((size_t)(base + q0 + l15) * 8 + h) * 64;
        #pragma unroll
        for (int s = 0; s < 2; ++s) {
            qh[s] = *(const bf16x8*)&Qpk_hi[ro + s * 32 + lg * 8];
            ql[s] = *(const bf16x8*)&Qpk_lo[ro + s * 32 + lg * 8];
        }
    }

    // ---- hoisted staging: 12 chunks/tile, wave w owns c = w, w+4, w+8 ----
    const u16* sp[3]; int sstep[3];
    u16* dp0[3]; u16* dp1[3];
    {
        const int k00 = ks * 1024;
        #pragma unroll
        for (int i2 = 0; i2 < 3; ++i2) {
            int c = w + i2 * 4;
            if (c < 8) {
                int r0 = c * 8, r = r0 + (l >> 3);
                int swz = ((l & 7) * 16) ^ ((r & 7) << 4);
                sp[i2] = Kpk_hi + ((size_t)(base + k00 + r) * 8 + h) * 64 + (swz >> 1);
                sstep[i2] = 32768;
                dp0[i2] = &KH[0][r0 * 64];
                dp1[i2] = &KH[1][r0 * 64];
            } else {
                int r0 = (c - 8) * 8, r = r0 + (l >> 3);
                int swz = ((l & 7) * 16) ^ ((r & 7) << 4);
                sp[i2] = Vt_hi + (((size_t)b * 8 + h) * 32 + r) * 2048 + k00 + (swz >> 1);
                sstep[i2] = 64;
                dp0[i2] = &VH[0][r0 * 64];
                dp1[i2] = &VH[1][r0 * 64];
            }
        }
    }

    auto stage = [&](u16* const (&dpx)[3]) {
        #pragma unroll
        for (int i2 = 0; i2 < 3; ++i2) { GL16(sp[i2], dpx[i2]); sp[i2] += sstep[i2]; }
    };

    float m_i = -INFINITY, l_i = 0.f;   // per-lane, q = l15 (x4 replicas), log2 domain
    f32x4 o0 = {0.f, 0.f, 0.f, 0.f}, o1 = {0.f, 0.f, 0.f, 0.f};

    auto compute_tile = [&](const u16* KHc, const u16* VHc) {
        // ---- S^T = K @ Q^T: ta[cj][r] = S[k = cj*16+lg*4+r][q = l15] ----
        f32x4 ta[4] = {{0.f,0.f,0.f,0.f},{0.f,0.f,0.f,0.f},{0.f,0.f,0.f,0.f},{0.f,0.f,0.f,0.f}};
        #pragma unroll
        for (int s = 0; s < 2; ++s) {
            int byo = s * 64 + lg * 16;
            #pragma unroll
            for (int cj = 0; cj < 4; ++cj) {
                bf16x8 kh = *(const bf16x8*)((const char*)KHc + swzb(cj * 16 + l15, byo));
                ta[cj] = MFMA16(kh, qh[s], ta[cj]);
                ta[cj] = MFMA16(kh, ql[s], ta[cj]);
            }
        }

        // ---- lane-local softmax (log2 domain), defer-max THR=8 ----
        float t0 = fmaxf(fmaxf(ta[0][0], ta[0][1]), fmaxf(ta[0][2], ta[0][3]));
        float t1 = fmaxf(fmaxf(ta[1][0], ta[1][1]), fmaxf(ta[1][2], ta[1][3]));
        float t2 = fmaxf(fmaxf(ta[2][0], ta[2][1]), fmaxf(ta[2][2], ta[2][3]));
        float t3 = fmaxf(fmaxf(ta[3][0], ta[3][1]), fmaxf(ta[3][2], ta[3][3]));
        float tmax = fmaxf(fmaxf(t0, t1), fmaxf(t2, t3));
        tmax = fmaxf(tmax, __shfl_xor(tmax, 16));
        tmax = fmaxf(tmax, __shfl_xor(tmax, 32));
        if (!__all(tmax <= m_i + 8.0f)) {
            float mnew = fmaxf(m_i, tmax);
            float sc = EXP2(m_i - mnew);
            l_i *= sc;
            #pragma unroll
            for (int r = 0; r < 4; ++r) {
                float fac = __shfl(sc, lg * 4 + r);
                o0[r] *= fac;
                o1[r] *= fac;
            }
            m_i = mnew;
        }
        #pragma unroll
        for (int cj = 0; cj < 4; ++cj)
            #pragma unroll
            for (int r = 0; r < 4; ++r)
                ta[cj][r] = EXP2(ta[cj][r] - m_i);
        float s0 = (ta[0][0] + ta[0][1]) + (ta[0][2] + ta[0][3]);
        float s1 = (ta[1][0] + ta[1][1]) + (ta[1][2] + ta[1][3]);
        float s2 = (ta[2][0] + ta[2][1]) + (ta[2][2] + ta[2][3]);
        float s3 = (ta[3][0] + ta[3][1]) + (ta[3][2] + ta[3][3]);
        float tsum = (s0 + s1) + (s2 + s3);
        tsum += __shfl_xor(tsum, 16);
        tsum += __shfl_xor(tsum, 32);
        l_i += tsum;

        // ---- pack P (hi only) -> per-wave LDS: 4 x ds_write_b64 ----
        #pragma unroll
        for (int cj = 0; cj < 4; ++cj) {
            uint2 pv = {pkbf2(ta[cj][0], ta[cj][1]), pkbf2(ta[cj][2], ta[cj][3])};
            *(uint2*)((char*)PH[w] + swzb(l15, cj * 32 + lg * 8)) = pv;
        }

        // ---- O += P @ Vh (16q x 32d) ----
        #pragma unroll
        for (int kq = 0; kq < 2; ++kq) {
            int byo = kq * 64 + lg * 16;
            bf16x8 pa  = *(const bf16x8*)((const char*)PH[w] + swzb(l15, byo));
            bf16x8 vh0 = *(const bf16x8*)((const char*)VHc + swzb(l15, byo));
            bf16x8 vh1 = *(const bf16x8*)((const char*)VHc + swzb(16 + l15, byo));
            o0 = MFMA16(pa, vh0, o0);
            o1 = MFMA16(pa, vh1, o1);
        }
    };

    // ---- 2-phase pipelined main loop: 16 tiles, 1 barrier per tile ----
    stage(dp0);                       // prologue: tile 0 -> buf 0
    #pragma unroll 1
    for (int it2 = 0; it2 < 8; ++it2) {
        __syncthreads();              // tile 2*it2 landed in buf0; buf1 free
        stage(dp1);                   // prefetch tile 2*it2+1 -> buf1
        compute_tile(KH[0], VH[0]);
        __syncthreads();              // tile 2*it2+1 landed; buf0 free
        if (it2 < 7) stage(dp0);      // prefetch tile 2*it2+2 -> buf0
        compute_tile(KH[1], VH[1]);
    }

    // ---- epilogue: write unnormalized partial O + (m,l) ----
    const int pb = (b * 8 + h) * 2 + ks;
    #pragma unroll
    for (int r = 0; r < 4; ++r) {
        int row = q0 + lg * 4 + r;
        size_t ob = ((size_t)pb * 2048 + row) * 32;
        Opart[ob + l15]      = o0[r];
        Opart[ob + 16 + l15] = o1[r];
    }
    if (l < 16) {
        int row = q0 + l15;
        float2 ml = {m_i, l_i};
        *(float2*)&Oml[((size_t)pb * 2048 + row) * 2] = ml;
    }
}

// ---------------------------------------------------------------------------
// Merge 2 k-split partials -> normalized ctx (split bf16). m is log2-domain.
// grid (64, 8, 2), 256 thr.
// ---------------------------------------------------------------------------
__global__ __launch_bounds__(256) void attn_merge(
    const float* __restrict__ Opart, const float* __restrict__ Oml,
    u16* __restrict__ Cx_hi, u16* __restrict__ Cx_lo)
{
    const int t = threadIdx.x;
    const int d = t & 31, rg = t >> 5;
    const int h = blockIdx.y, b = blockIdx.z;
    const int pb = (b * 8 + h) * 2;
    #pragma unroll
    for (int rr = 0; rr < 4; ++rr) {
        int row = blockIdx.x * 32 + rr * 8 + rg;
        float m[2], lv[2];
        #pragma unroll
        for (int i = 0; i < 2; ++i) {
            size_t mb = ((size_t)(pb + i) * 2048 + row) * 2;
            m[i]  = Oml[mb];
            lv[i] = Oml[mb + 1];
        }
        float M = fmaxf(m[0], m[1]);
        float w0 = exp2f(m[0] - M), w1 = exp2f(m[1] - M);
        float L = lv[0] * w0 + lv[1] * w1;
        float o = w0 * Opart[((size_t)pb * 2048 + row) * 32 + d]
                + w1 * Opart[((size_t)(pb + 1) * 2048 + row) * 32 + d];
        float y = o / L;
        u32 hb = bf16rne(y);
        size_t orow = (size_t)(b * 2048 + row) * 256 + h * 32 + d;
        Cx_hi[orow] = (u16)hb;
        Cx_lo[orow] = (u16)bf16rne(y - bf16tof(hb));
    }
}

// ---------------------------------------------------------------------------
// Final GEMM v2 (R19-proven): M-tile 32, grid (4, 128) = 2 blocks/CU.
// Wave w: rows (w&1)*16, cols (w>>1)*32. LDS 24 KB.
// ---------------------------------------------------------------------------
__global__ __launch_bounds__(256, 2) void gemm_out_mfma2(
    const u16* __restrict__ Xhi, const u16* __restrict__ Xlo,
    const u16* __restrict__ Wth, const u16* __restrict__ Wtl,
    const float* __restrict__ bias, float* __restrict__ out)
{
    __shared__ u16 XH[32 * 64], XL[32 * 64];
    __shared__ u16 WH[64 * 64], WL[64 * 64];

    const int t = threadIdx.x, w = t >> 6, l = t & 63;
    const int l15 = l & 15, lg = l >> 4;
    const int bn = blockIdx.x * 64, bm = blockIdx.y * 32;

    const int mr = (w & 1) * 16;       // wave row base within tile
    const int nc = (w >> 1) * 32;      // wave col base within tile

    const int lr = l >> 3;
    const int swz = ((l & 7) * 16) ^ (lr << 4);
    const u16* sp[6]; u16* dp[6];
    #pragma unroll
    for (int j = 0; j < 6; ++j) {
        int c = w * 6 + j;
        if (c < 8) {
            sp[j] = Wth + (size_t)(bn + c * 8 + lr) * 256 + (swz >> 1);
            dp[j] = &WH[c * 512];
        } else if (c < 16) {
            sp[j] = Wtl + (size_t)(bn + (c - 8) * 8 + lr) * 256 + (swz >> 1);
            dp[j] = &WL[(c - 8) * 512];
        } else if (c < 20) {
            sp[j] = Xhi + (size_t)(bm + (c - 16) * 8 + lr) * 256 + (swz >> 1);
            dp[j] = &XH[(c - 16) * 512];
        } else {
            sp[j] = Xlo + (size_t)(bm + (c - 20) * 8 + lr) * 256 + (swz >> 1);
            dp[j] = &XL[(c - 20) * 512];
        }
    }

    f32x4 acc[2] = {{0.f,0.f,0.f,0.f},{0.f,0.f,0.f,0.f}};

    for (int k0 = 0; k0 < 256; k0 += 64) {
        __syncthreads();
        #pragma unroll
        for (int j = 0; j < 6; ++j) { GL16(sp[j], dp[j]); sp[j] += 64; }
        __syncthreads();
        #pragma unroll
        for (int s = 0; s < 2; ++s) {
            int byo = s * 64 + lg * 16;
            bf16x8 ah = *(const bf16x8*)((const char*)XH + swzb(mr + l15, byo));
            bf16x8 al = *(const bf16x8*)((const char*)XL + swzb(mr + l15, byo));
            #pragma unroll
            for (int cj = 0; cj < 2; ++cj) {
                bf16x8 bh = *(const bf16x8*)((const char*)WH + swzb(nc + cj * 16 + l15, byo));
                bf16x8 bl = *(const bf16x8*)((const char*)WL + swzb(nc + cj * 16 + l15, byo));
                acc[cj] = MFMA16(ah, bh, acc[cj]);
                acc[cj] = MFMA16(al, bh, acc[cj]);
                acc[cj] = MFMA16(ah, bl, acc[cj]);
            }
        }
    }

    #pragma unroll
    for (int cj = 0; cj < 2; ++cj) {
        float bv = bias[bn + nc + cj * 16 + l15];
        #pragma unroll
        for (int r = 0; r < 4; ++r) {
            int row = bm + mr + lg * 4 + r;
            out[(size_t)row * 256 + bn + nc + cj * 16 + l15] = acc[cj][r] + bv;
        }
    }
}

// ---------------------------------------------------------------------------
extern "C" void kernel_launch(void* const* d_in, const int* in_sizes, int n_in,
                              void* d_out, int out_size, void* d_ws, size_t ws_size,
                              hipStream_t stream) {
    const float* A     = (const float*)d_in[0];
    const float* B     = (const float*)d_in[1];
    const float* Wq_aa = (const float*)d_in[2];
    const float* bq_aa = (const float*)d_in[3];
    const float* Wk_aa = (const float*)d_in[4];
    const float* bk_aa = (const float*)d_in[5];
    const float* Wv_a  = (const float*)d_in[6];
    const float* bv_a  = (const float*)d_in[7];
    const float* Wk_ab = (const float*)d_in[8];
    const float* bk_ab = (const float*)d_in[9];
    const float* Wq_bb = (const float*)d_in[10];
    const float* bq_bb = (const float*)d_in[11];
    const float* Wo    = (const float*)d_in[12];
    const float* bo    = (const float*)d_in[13];
    float* out = (float*)d_out;

    char* p = (char*)d_ws;
    u16* spare0 = (u16*)p; p += 6291456;   // Opart/Oml alias region
    u16* spare1 = (u16*)p; p += 6291456;
    u16* spare2 = (u16*)p; p += 6291456;
    u16* spare3 = (u16*)p; p += 6291456;
    u16* W5t_hi = (u16*)p; p += 1966080;
    u16* W5t_lo = (u16*)p; p += 1966080;   // no longer written (uniform 2-term)
    u16* Wot_hi = (u16*)p; p += 131072;
    u16* Wot_lo = (u16*)p; p += 131072;
    u16* Qpk_hi = (u16*)p; p += 4194304;
    u16* Qpk_lo = (u16*)p; p += 4194304;
    u16* Kpk_hi = (u16*)p; p += 4194304;
    u16* Kpk_lo = (u16*)p; p += 4194304;   // unused (layout stability)
    u16* Vt_hi  = (u16*)p; p += 2097152;
    u16* Vt_lo  = (u16*)p; p += 2097152;   // unused
    u16* Cx_hi  = (u16*)p; p += 2097152;
    u16* Cx_lo  = (u16*)p; p += 2097152;
    (void)spare0; (void)spare1; (void)spare2; (void)spare3;
    (void)Kpk_lo; (void)Vt_lo;

    // k-split partials alias the spare region (nothing else touches it):
    // Opart 32*2048*32*4 = 8.39 MB, Oml 0.52 MB
    float* Opart = (float*)d_ws;
    float* Oml   = (float*)((char*)d_ws + 8388608);

    conv_w<<<dim3(12, 4, 6), 256, 0, stream>>>(Wq_aa, Wk_aa, Wv_a, Wk_ab, Wq_bb, Wo,
                                               W5t_hi, W5t_lo, Wot_hi, Wot_lo);
    proj_fused<<<dim3(1280), 256, 0, stream>>>(A, B, W5t_hi,
                                               bq_aa, bk_aa, bv_a, bk_ab, bq_bb,
                                               Qpk_hi, Qpk_lo, Kpk_hi, Vt_hi);
    attn_mfma8<<<dim3(1024), 256, 0, stream>>>(Qpk_hi, Qpk_lo, Kpk_hi, Vt_hi,
                                               Opart, Oml);
    attn_merge<<<dim3(64, 8, 2), 256, 0, stream>>>(Opart, Oml, Cx_hi, Cx_lo);
    gemm_out_mfma2<<<dim3(4, 128), 256, 0, stream>>>(Cx_hi, Cx_lo, Wot_hi, Wot_lo,
                                                     bo, out);
}

// Round 21
// 77.408 us; speedup vs baseline: 1.1402x; 1.1402x over previous
//
#include <hip/hip_runtime.h>
#include <hip/hip_bf16.h>
#include <math.h>

#define SCALE  0.17677669529663687f            // 1/sqrt(32)
#define QSCALE 0.25501817444361255f            // SCALE * log2(e)  (exp2 domain)

#if __has_builtin(__builtin_amdgcn_exp2f)
#define EXP2(x) __builtin_amdgcn_exp2f(x)
#else
#define EXP2(x) exp2f(x)
#endif

typedef __attribute__((ext_vector_type(8))) short bf16x8;
typedef __attribute__((ext_vector_type(4))) float f32x4;
typedef unsigned int u32;
typedef unsigned short u16;

#define MFMA16(a, b, c) __builtin_amdgcn_mfma_f32_16x16x32_bf16(a, b, c, 0, 0, 0)

__device__ inline u32 bf16rne(float x) {
    u32 u = __float_as_uint(x);
    return (u + 0x7FFFu + ((u >> 16) & 1u)) >> 16;
}
__device__ inline float bf16tof(u32 h) { return __uint_as_float(h << 16); }
// pack 2 floats -> 2 bf16 (RNE) in one u32 (lo = a)
__device__ inline u32 pkbf2(float a, float b) {
    union { __hip_bfloat162 h; u32 u; } cv;
    cv.h = __float22bfloat162_rn(make_float2(a, b));
    return cv.u;
}
// byte addr within a tile of 128-byte rows, XOR-swizzled (G4 / T2)
__device__ inline int swzb(int row, int b) { return row * 128 + (b ^ ((row & 7) << 4)); }

typedef __attribute__((address_space(1))) const u32 gu32;
typedef __attribute__((address_space(3))) u32 lu32;
#define GL16(g, l) __builtin_amdgcn_global_load_lds((gu32*)(const void*)(g), (lu32*)(void*)(l), 16, 0, 0)

// ---------------------------------------------------------------------------
// Convert + transpose weights: g<5: W[768][256] -> Wt[g][256][768] HI only
// (proj is uniform 2-term); g==5: Wo -> Wot hi+lo.  grid (12, 4, 6).
// ---------------------------------------------------------------------------
__global__ __launch_bounds__(256) void conv_w(
    const float* __restrict__ W0, const float* __restrict__ W1,
    const float* __restrict__ W2, const float* __restrict__ W3,
    const float* __restrict__ W4, const float* __restrict__ Wo,
    u16* __restrict__ W5t_hi, u16* __restrict__ W5t_lo,
    u16* __restrict__ Wot_hi, u16* __restrict__ Wot_lo)
{
    const int g = blockIdx.z;
    const float* W; int K; u16 *dh, *dl;
    switch (g) {
        case 0: W = W0; K = 768; dh = W5t_hi;              dl = nullptr;  break;
        case 1: W = W1; K = 768; dh = W5t_hi + 196608;     dl = nullptr;  break;
        case 2: W = W2; K = 768; dh = W5t_hi + 2 * 196608; dl = nullptr;  break;
        case 3: W = W3; K = 768; dh = W5t_hi + 3 * 196608; dl = nullptr;  break;
        case 4: W = W4; K = 768; dh = W5t_hi + 4 * 196608; dl = nullptr;  break;
        default: W = Wo; K = 256; dh = Wot_hi; dl = Wot_lo; break;
    }
    (void)W5t_lo;
    const int k0 = blockIdx.x * 64, n0 = blockIdx.y * 64;
    if (k0 >= K) return;
    __shared__ float T[64][65];
    const int t = threadIdx.x;
    #pragma unroll
    for (int rep = 0; rep < 4; ++rep) {
        int kr = rep * 16 + (t >> 4);
        int nc = (t & 15) * 4;
        float4 f = *(const float4*)&W[(size_t)(k0 + kr) * 256 + n0 + nc];
        T[kr][nc] = f.x; T[kr][nc + 1] = f.y; T[kr][nc + 2] = f.z; T[kr][nc + 3] = f.w;
    }
    __syncthreads();
    #pragma unroll
    for (int rep = 0; rep < 4; ++rep) {
        int idx = rep * 256 + t;
        int n = idx >> 4, kq = (idx & 15) * 4;
        float v0 = T[kq + 0][n], v1 = T[kq + 1][n], v2 = T[kq + 2][n], v3 = T[kq + 3][n];
        u32 h0 = bf16rne(v0), h1 = bf16rne(v1), h2 = bf16rne(v2), h3 = bf16rne(v3);
        ushort4 hv = {(u16)h0, (u16)h1, (u16)h2, (u16)h3};
        size_t o = (size_t)(n0 + n) * K + k0 + kq;
        *(ushort4*)&dh[o] = hv;
        if (dl) {
            ushort4 lv = {(u16)bf16rne(v0 - bf16tof(h0)), (u16)bf16rne(v1 - bf16tof(h1)),
                          (u16)bf16rne(v2 - bf16tof(h2)), (u16)bf16rne(v3 - bf16tof(h3))};
            *(ushort4*)&dl[o] = lv;
        }
    }
}

// ---------------------------------------------------------------------------
// Fused projection v3 (R19-proven): uniform 2-term ((xh+xl)*wh), W dbuf
// (one barrier per k-step), X wave-private reg-staged. grid 640 1-D,
// XCD decode. LDS: XH 8K + XL 8K + W 2x16K = 48 KB -> 3 blocks/CU.
// ---------------------------------------------------------------------------
__global__ __launch_bounds__(256, 3) void proj_fused(
    const float* __restrict__ A, const float* __restrict__ Bm,
    const u16* __restrict__ W5t_hi,
    const float* __restrict__ b0, const float* __restrict__ b1,
    const float* __restrict__ b2, const float* __restrict__ b3,
    const float* __restrict__ b4,
    u16* __restrict__ Qpk_hi, u16* __restrict__ Qpk_lo,
    u16* __restrict__ Kpk_hi, u16* __restrict__ Vt_hi)
{
    __shared__ u16 XH[64 * 64], XL[64 * 64];
    __shared__ u16 WB[2][128 * 64];

    const int t = threadIdx.x, w = t >> 6, l = t & 63;
    const int l15 = l & 15, lg = l >> 4;

    const int i = blockIdx.x;                 // 0..639
    const int v = (i & 7) * 80 + (i >> 3);    // bijective (640 = 8*80)
    const int unit = v % 10;
    const int g = unit >> 1;
    const int half = unit & 1;
    const int bm = (v / 10) * 64;

    const float* X = (g == 4) ? Bm : A;
    const u16* Wh = W5t_hi + (size_t)g * 196608 + (size_t)half * 98304;
    const float* bias;
    switch (g) {
        case 0: bias = b0; break;
        case 1: bias = b1; break;
        case 2: bias = b2; break;
        case 3: bias = b3; break;
        default: bias = b4; break;
    }
    const bool isq = (g == 0 || g == 3);

    const int lr = l >> 3;                                  // 0..7
    const int wswz = ((l & 7) * 16) ^ ((lr & 7) << 4);
    const u16* whp = Wh + (size_t)lr * 768 + (wswz >> 1);

    const int xr = t >> 2;
    const float* xp = X + (size_t)(bm + xr) * 768 + (t & 3) * 16;
    const int xb0 = swzb(xr, (t & 3) * 32);
    const int xb1 = swzb(xr, (t & 3) * 32 + 16);

    f32x4 acc[8];
    #pragma unroll
    for (int cg = 0; cg < 8; ++cg) acc[cg] = (f32x4){0.f, 0.f, 0.f, 0.f};

    float4 fc0, fc1, fc2, fc3;
    auto load_x = [&]() {
        fc0 = ((const float4*)xp)[0]; fc1 = ((const float4*)xp)[1];
        fc2 = ((const float4*)xp)[2]; fc3 = ((const float4*)xp)[3];
        xp += 64;
    };
    auto convert_x = [&]() {
        float va[16] = {fc0.x, fc0.y, fc0.z, fc0.w, fc1.x, fc1.y, fc1.z, fc1.w,
                        fc2.x, fc2.y, fc2.z, fc2.w, fc3.x, fc3.y, fc3.z, fc3.w};
        u32 hp[8], lp[8];
        #pragma unroll
        for (int jj = 0; jj < 8; ++jj) {
            float a = va[2 * jj], bq = va[2 * jj + 1];
            u32 hq = pkbf2(a, bq);
            hp[jj] = hq;
            lp[jj] = pkbf2(a - bf16tof(hq & 0xffffu), bq - bf16tof(hq >> 16));
        }
        uint4 u;
        u.x = hp[0]; u.y = hp[1]; u.z = hp[2]; u.w = hp[3];
        *(uint4*)((char*)XH + xb0) = u;
        u.x = hp[4]; u.y = hp[5]; u.z = hp[6]; u.w = hp[7];
        *(uint4*)((char*)XH + xb1) = u;
        u.x = lp[0]; u.y = lp[1]; u.z = lp[2]; u.w = lp[3];
        *(uint4*)((char*)XL + xb0) = u;
        u.x = lp[4]; u.y = lp[5]; u.z = lp[6]; u.w = lp[7];
        *(uint4*)((char*)XL + xb1) = u;
    };
    auto stage_w = [&](u16* buf) {
        #pragma unroll
        for (int j = 0; j < 4; ++j) {
            int c = w * 4 + j;
            GL16(whp + (size_t)c * 6144, &buf[c * 512]);
        }
        whp += 64;
    };

    // ---- prologue: X(0) regs -> LDS; W(0) -> buf0; X(1) regs ----
    load_x();
    stage_w(WB[0]);
    convert_x();
    load_x();

    for (int ks = 0; ks < 12; ++ks) {
        __syncthreads();   // W(ks) landed; waves done reading WB[(ks+1)&1]
        if (ks < 11) stage_w(WB[(ks + 1) & 1]);

        // ---- compute(ks): (xh + xl) * wh, rows w*16.., 128 cols ----
        const char* Wc = (const char*)WB[ks & 1];
        #pragma unroll
        for (int s = 0; s < 2; ++s) {
            int byo = s * 64 + lg * 16;
            bf16x8 ah = *(const bf16x8*)((const char*)XH + swzb(w * 16 + l15, byo));
            bf16x8 al = *(const bf16x8*)((const char*)XL + swzb(w * 16 + l15, byo));
            #pragma unroll
            for (int cg = 0; cg < 8; ++cg) {
                bf16x8 bh = *(const bf16x8*)(Wc + swzb(cg * 16 + l15, byo));
                acc[cg] = MFMA16(ah, bh, acc[cg]);
                acc[cg] = MFMA16(al, bh, acc[cg]);
            }
        }

        // ---- refill X (wave-private: in-order DS, no barrier needed) ----
        if (ks < 11) {
            convert_x();
            if (ks < 10) load_x();
        }
    }

    float biasv[8];
    #pragma unroll
    for (int cg = 0; cg < 8; ++cg) biasv[cg] = bias[half * 128 + cg * 16 + l15];

    if (g != 2) {
        u16* Dh = isq ? Qpk_hi : Kpk_hi;
        const int dofs = (g == 3 || g == 4) ? 32 : 0;
        #pragma unroll
        for (int cg = 0; cg < 8; ++cg) {
            int c = half * 128 + cg * 16 + l15;
            int h = c >> 5, d = (c & 31) + dofs;
            #pragma unroll
            for (int r = 0; r < 4; ++r) {
                int row = bm + w * 16 + lg * 4 + r;
                float y = acc[cg][r] + biasv[cg];
                if (isq) y *= QSCALE;       // exp2-domain logits
                u32 hb = bf16rne(y);
                size_t o = ((size_t)row * 8 + h) * 64 + d;
                Dh[o] = (u16)hb;
                if (isq) Qpk_lo[o] = (u16)bf16rne(y - bf16tof(hb));
            }
        }
    } else {
        // V: transpose [64 k][128 d] -> [128 d][64 k] via WB[0] (done with W)
        __syncthreads();
        #pragma unroll
        for (int cg = 0; cg < 8; ++cg) {
            int dl = cg * 16 + l15;            // 0..127 local
            #pragma unroll
            for (int r = 0; r < 4; ++r) {
                int kl = w * 16 + lg * 4 + r;  // 0..63
                float y = acc[cg][r] + biasv[cg];
                int byo = (2 * kl) ^ ((dl & 7) << 4);
                *(u16*)((char*)WB[0] + dl * 128 + byo) = (u16)bf16rne(y);
            }
        }
        __syncthreads();
        const int bb = bm >> 11, kb = bm & 2047;
        #pragma unroll
        for (int rep = 0; rep < 8; ++rep) {
            int idx = rep * 256 + t;           // 0..2047
            int dl = idx >> 4;                 // 0..127 local
            int kq = idx & 15;                 // 4-k chunk
            int dg = half * 128 + dl;
            int h = dg >> 5, d = dg & 31;
            int byo = (8 * kq) ^ ((dl & 7) << 4);
            ushort4 hv = *(const ushort4*)((const char*)WB[0] + dl * 128 + byo);
            size_t o = (((size_t)bb * 8 + h) * 32 + d) * 2048 + kb + kq * 4;
            *(ushort4*)&Vt_hi[o] = hv;
        }
    }
}

// ---------------------------------------------------------------------------
// MFMA flash attention v8 (anchor, unchanged): 2-phase dbuf prefetch,
// k-split 2, XCD swizzle, swapped QK^T, exp2 domain, defer-max. No setprio.
// grid 1024. LDS = 32 KB -> 4 blocks/CU.
// ---------------------------------------------------------------------------
__global__ __launch_bounds__(256, 4) void attn_mfma8(
    const u16* __restrict__ Qpk_hi, const u16* __restrict__ Qpk_lo,
    const u16* __restrict__ Kpk_hi, const u16* __restrict__ Vt_hi,
    float* __restrict__ Opart, float* __restrict__ Oml)
{
    __shared__ u16 KH[2][64 * 64], VH[2][32 * 64];
    __shared__ u16 PH[4][16 * 64];

    const int t = threadIdx.x, w = t >> 6, l = t & 63;
    const int l15 = l & 15, lg = l >> 4;

    // XCD-aware decode (T1): i%8 = XCD; 128 consecutive v per XCD.
    const int i = blockIdx.x;                  // 0..1023
    const int v = (i & 7) * 128 + (i >> 3);    // bijective (1024 % 8 == 0)
    const int panel = v >> 5;                  // 0..31 = (h, b, ks)
    const int qb   = v & 31;                   // q-block within panel
    const int h = panel >> 2;
    const int z = panel & 3;
    const int b = z >> 1, ks = z & 1;
    const int q0 = qb * 64 + w * 16;
    const int base = b * 2048;

    // Q fragments (QSCALE pre-folded)
    bf16x8 qh[2], ql[2];
    {
        size_t ro = ((size_t)(base + q0 + l15) * 8 + h) * 64;
        #pragma unroll
        for (int s = 0; s < 2; ++s) {
            qh[s] = *(const bf16x8*)&Qpk_hi[ro + s * 32 + lg * 8];
            ql[s] = *(const bf16x8*)&Qpk_lo[ro + s * 32 + lg * 8];
        }
    }

    // ---- hoisted staging: 12 chunks/tile, wave w owns c = w, w+4, w+8 ----
    const u16* sp[3]; int sstep[3];
    u16* dp0[3]; u16* dp1[3];
    {
        const int k00 = ks * 1024;
        #pragma unroll
        for (int i2 = 0; i2 < 3; ++i2) {
            int c = w + i2 * 4;
            if (c < 8) {
                int r0 = c * 8, r = r0 + (l >> 3);
                int swz = ((l & 7) * 16) ^ ((r & 7) << 4);
                sp[i2] = Kpk_hi + ((size_t)(base + k00 + r) * 8 + h) * 64 + (swz >> 1);
                sstep[i2] = 32768;
                dp0[i2] = &KH[0][r0 * 64];
                dp1[i2] = &KH[1][r0 * 64];
            } else {
                int r0 = (c - 8) * 8, r = r0 + (l >> 3);
                int swz = ((l & 7) * 16) ^ ((r & 7) << 4);
                sp[i2] = Vt_hi + (((size_t)b * 8 + h) * 32 + r) * 2048 + k00 + (swz >> 1);
                sstep[i2] = 64;
                dp0[i2] = &VH[0][r0 * 64];
                dp1[i2] = &VH[1][r0 * 64];
            }
        }
    }

    auto stage = [&](u16* const (&dpx)[3]) {
        #pragma unroll
        for (int i2 = 0; i2 < 3; ++i2) { GL16(sp[i2], dpx[i2]); sp[i2] += sstep[i2]; }
    };

    float m_i = -INFINITY, l_i = 0.f;   // per-lane, q = l15 (x4 replicas), log2 domain
    f32x4 o0 = {0.f, 0.f, 0.f, 0.f}, o1 = {0.f, 0.f, 0.f, 0.f};

    auto compute_tile = [&](const u16* KHc, const u16* VHc) {
        // ---- S^T = K @ Q^T: ta[cj][r] = S[k = cj*16+lg*4+r][q = l15] ----
        f32x4 ta[4] = {{0.f,0.f,0.f,0.f},{0.f,0.f,0.f,0.f},{0.f,0.f,0.f,0.f},{0.f,0.f,0.f,0.f}};
        #pragma unroll
        for (int s = 0; s < 2; ++s) {
            int byo = s * 64 + lg * 16;
            #pragma unroll
            for (int cj = 0; cj < 4; ++cj) {
                bf16x8 kh = *(const bf16x8*)((const char*)KHc + swzb(cj * 16 + l15, byo));
                ta[cj] = MFMA16(kh, qh[s], ta[cj]);
                ta[cj] = MFMA16(kh, ql[s], ta[cj]);
            }
        }

        // ---- lane-local softmax (log2 domain), defer-max THR=8 ----
        float t0 = fmaxf(fmaxf(ta[0][0], ta[0][1]), fmaxf(ta[0][2], ta[0][3]));
        float t1 = fmaxf(fmaxf(ta[1][0], ta[1][1]), fmaxf(ta[1][2], ta[1][3]));
        float t2 = fmaxf(fmaxf(ta[2][0], ta[2][1]), fmaxf(ta[2][2], ta[2][3]));
        float t3 = fmaxf(fmaxf(ta[3][0], ta[3][1]), fmaxf(ta[3][2], ta[3][3]));
        float tmax = fmaxf(fmaxf(t0, t1), fmaxf(t2, t3));
        tmax = fmaxf(tmax, __shfl_xor(tmax, 16));
        tmax = fmaxf(tmax, __shfl_xor(tmax, 32));
        if (!__all(tmax <= m_i + 8.0f)) {
            float mnew = fmaxf(m_i, tmax);
            float sc = EXP2(m_i - mnew);
            l_i *= sc;
            #pragma unroll
            for (int r = 0; r < 4; ++r) {
                float fac = __shfl(sc, lg * 4 + r);
                o0[r] *= fac;
                o1[r] *= fac;
            }
            m_i = mnew;
        }
        #pragma unroll
        for (int cj = 0; cj < 4; ++cj)
            #pragma unroll
            for (int r = 0; r < 4; ++r)
                ta[cj][r] = EXP2(ta[cj][r] - m_i);
        float s0 = (ta[0][0] + ta[0][1]) + (ta[0][2] + ta[0][3]);
        float s1 = (ta[1][0] + ta[1][1]) + (ta[1][2] + ta[1][3]);
        float s2 = (ta[2][0] + ta[2][1]) + (ta[2][2] + ta[2][3]);
        float s3 = (ta[3][0] + ta[3][1]) + (ta[3][2] + ta[3][3]);
        float tsum = (s0 + s1) + (s2 + s3);
        tsum += __shfl_xor(tsum, 16);
        tsum += __shfl_xor(tsum, 32);
        l_i += tsum;

        // ---- pack P (hi only) -> per-wave LDS: 4 x ds_write_b64 ----
        #pragma unroll
        for (int cj = 0; cj < 4; ++cj) {
            uint2 pv = {pkbf2(ta[cj][0], ta[cj][1]), pkbf2(ta[cj][2], ta[cj][3])};
            *(uint2*)((char*)PH[w] + swzb(l15, cj * 32 + lg * 8)) = pv;
        }

        // ---- O += P @ Vh (16q x 32d) ----
        #pragma unroll
        for (int kq = 0; kq < 2; ++kq) {
            int byo = kq * 64 + lg * 16;
            bf16x8 pa  = *(const bf16x8*)((const char*)PH[w] + swzb(l15, byo));
            bf16x8 vh0 = *(const bf16x8*)((const char*)VHc + swzb(l15, byo));
            bf16x8 vh1 = *(const bf16x8*)((const char*)VHc + swzb(16 + l15, byo));
            o0 = MFMA16(pa, vh0, o0);
            o1 = MFMA16(pa, vh1, o1);
        }
    };

    // ---- 2-phase pipelined main loop: 16 tiles, 1 barrier per tile ----
    stage(dp0);                       // prologue: tile 0 -> buf 0
    #pragma unroll 1
    for (int it2 = 0; it2 < 8; ++it2) {
        __syncthreads();              // tile 2*it2 landed in buf0; buf1 free
        stage(dp1);                   // prefetch tile 2*it2+1 -> buf1
        compute_tile(KH[0], VH[0]);
        __syncthreads();              // tile 2*it2+1 landed; buf0 free
        if (it2 < 7) stage(dp0);      // prefetch tile 2*it2+2 -> buf0
        compute_tile(KH[1], VH[1]);
    }

    // ---- epilogue: write unnormalized partial O + (m,l) ----
    const int pb = (b * 8 + h) * 2 + ks;
    #pragma unroll
    for (int r = 0; r < 4; ++r) {
        int row = q0 + lg * 4 + r;
        size_t ob = ((size_t)pb * 2048 + row) * 32;
        Opart[ob + l15]      = o0[r];
        Opart[ob + 16 + l15] = o1[r];
    }
    if (l < 16) {
        int row = q0 + l15;
        float2 ml = {m_i, l_i};
        *(float2*)&Oml[((size_t)pb * 2048 + row) * 2] = ml;
    }
}

// ---------------------------------------------------------------------------
// Merge 2 k-split partials -> normalized ctx (split bf16). m is log2-domain.
// grid (64, 8, 2), 256 thr.
// ---------------------------------------------------------------------------
__global__ __launch_bounds__(256) void attn_merge(
    const float* __restrict__ Opart, const float* __restrict__ Oml,
    u16* __restrict__ Cx_hi, u16* __restrict__ Cx_lo)
{
    const int t = threadIdx.x;
    const int d = t & 31, rg = t >> 5;
    const int h = blockIdx.y, b = blockIdx.z;
    const int pb = (b * 8 + h) * 2;
    #pragma unroll
    for (int rr = 0; rr < 4; ++rr) {
        int row = blockIdx.x * 32 + rr * 8 + rg;
        float m[2], lv[2];
        #pragma unroll
        for (int i = 0; i < 2; ++i) {
            size_t mb = ((size_t)(pb + i) * 2048 + row) * 2;
            m[i]  = Oml[mb];
            lv[i] = Oml[mb + 1];
        }
        float M = fmaxf(m[0], m[1]);
        float w0 = exp2f(m[0] - M), w1 = exp2f(m[1] - M);
        float L = lv[0] * w0 + lv[1] * w1;
        float o = w0 * Opart[((size_t)pb * 2048 + row) * 32 + d]
                + w1 * Opart[((size_t)(pb + 1) * 2048 + row) * 32 + d];
        float y = o / L;
        u32 hb = bf16rne(y);
        size_t orow = (size_t)(b * 2048 + row) * 256 + h * 32 + d;
        Cx_hi[orow] = (u16)hb;
        Cx_lo[orow] = (u16)bf16rne(y - bf16tof(hb));
    }
}

// ---------------------------------------------------------------------------
// Final GEMM v2 (R19-proven): M-tile 32, grid (4, 128) = 2 blocks/CU.
// Wave w: rows (w&1)*16, cols (w>>1)*32. LDS 24 KB.
// ---------------------------------------------------------------------------
__global__ __launch_bounds__(256, 2) void gemm_out_mfma2(
    const u16* __restrict__ Xhi, const u16* __restrict__ Xlo,
    const u16* __restrict__ Wth, const u16* __restrict__ Wtl,
    const float* __restrict__ bias, float* __restrict__ out)
{
    __shared__ u16 XH[32 * 64], XL[32 * 64];
    __shared__ u16 WH[64 * 64], WL[64 * 64];

    const int t = threadIdx.x, w = t >> 6, l = t & 63;
    const int l15 = l & 15, lg = l >> 4;
    const int bn = blockIdx.x * 64, bm = blockIdx.y * 32;

    const int mr = (w & 1) * 16;       // wave row base within tile
    const int nc = (w >> 1) * 32;      // wave col base within tile

    const int lr = l >> 3;
    const int swz = ((l & 7) * 16) ^ (lr << 4);
    const u16* sp[6]; u16* dp[6];
    #pragma unroll
    for (int j = 0; j < 6; ++j) {
        int c = w * 6 + j;
        if (c < 8) {
            sp[j] = Wth + (size_t)(bn + c * 8 + lr) * 256 + (swz >> 1);
            dp[j] = &WH[c * 512];
        } else if (c < 16) {
            sp[j] = Wtl + (size_t)(bn + (c - 8) * 8 + lr) * 256 + (swz >> 1);
            dp[j] = &WL[(c - 8) * 512];
        } else if (c < 20) {
            sp[j] = Xhi + (size_t)(bm + (c - 16) * 8 + lr) * 256 + (swz >> 1);
            dp[j] = &XH[(c - 16) * 512];
        } else {
            sp[j] = Xlo + (size_t)(bm + (c - 20) * 8 + lr) * 256 + (swz >> 1);
            dp[j] = &XL[(c - 20) * 512];
        }
    }

    f32x4 acc[2] = {{0.f,0.f,0.f,0.f},{0.f,0.f,0.f,0.f}};

    for (int k0 = 0; k0 < 256; k0 += 64) {
        __syncthreads();
        #pragma unroll
        for (int j = 0; j < 6; ++j) { GL16(sp[j], dp[j]); sp[j] += 64; }
        __syncthreads();
        #pragma unroll
        for (int s = 0; s < 2; ++s) {
            int byo = s * 64 + lg * 16;
            bf16x8 ah = *(const bf16x8*)((const char*)XH + swzb(mr + l15, byo));
            bf16x8 al = *(const bf16x8*)((const char*)XL + swzb(mr + l15, byo));
            #pragma unroll
            for (int cj = 0; cj < 2; ++cj) {
                bf16x8 bh = *(const bf16x8*)((const char*)WH + swzb(nc + cj * 16 + l15, byo));
                bf16x8 bl = *(const bf16x8*)((const char*)WL + swzb(nc + cj * 16 + l15, byo));
                acc[cj] = MFMA16(ah, bh, acc[cj]);
                acc[cj] = MFMA16(al, bh, acc[cj]);
                acc[cj] = MFMA16(ah, bl, acc[cj]);
            }
        }
    }

    #pragma unroll
    for (int cj = 0; cj < 2; ++cj) {
        float bv = bias[bn + nc + cj * 16 + l15];
        #pragma unroll
        for (int r = 0; r < 4; ++r) {
            int row = bm + mr + lg * 4 + r;
            out[(size_t)row * 256 + bn + nc + cj * 16 + l15] = acc[cj][r] + bv;
        }
    }
}

// ---------------------------------------------------------------------------
extern "C" void kernel_launch(void* const* d_in, const int* in_sizes, int n_in,
                              void* d_out, int out_size, void* d_ws, size_t ws_size,
                              hipStream_t stream) {
    const float* A     = (const float*)d_in[0];
    const float* B     = (const float*)d_in[1];
    const float* Wq_aa = (const float*)d_in[2];
    const float* bq_aa = (const float*)d_in[3];
    const float* Wk_aa = (const float*)d_in[4];
    const float* bk_aa = (const float*)d_in[5];
    const float* Wv_a  = (const float*)d_in[6];
    const float* bv_a  = (const float*)d_in[7];
    const float* Wk_ab = (const float*)d_in[8];
    const float* bk_ab = (const float*)d_in[9];
    const float* Wq_bb = (const float*)d_in[10];
    const float* bq_bb = (const float*)d_in[11];
    const float* Wo    = (const float*)d_in[12];
    const float* bo    = (const float*)d_in[13];
    float* out = (float*)d_out;

    char* p = (char*)d_ws;
    u16* spare0 = (u16*)p; p += 6291456;   // Opart/Oml alias region
    u16* spare1 = (u16*)p; p += 6291456;
    u16* spare2 = (u16*)p; p += 6291456;
    u16* spare3 = (u16*)p; p += 6291456;
    u16* W5t_hi = (u16*)p; p += 1966080;
    u16* W5t_lo = (u16*)p; p += 1966080;   // no longer written (uniform 2-term)
    u16* Wot_hi = (u16*)p; p += 131072;
    u16* Wot_lo = (u16*)p; p += 131072;
    u16* Qpk_hi = (u16*)p; p += 4194304;
    u16* Qpk_lo = (u16*)p; p += 4194304;
    u16* Kpk_hi = (u16*)p; p += 4194304;
    u16* Kpk_lo = (u16*)p; p += 4194304;   // unused (layout stability)
    u16* Vt_hi  = (u16*)p; p += 2097152;
    u16* Vt_lo  = (u16*)p; p += 2097152;   // unused
    u16* Cx_hi  = (u16*)p; p += 2097152;
    u16* Cx_lo  = (u16*)p; p += 2097152;
    (void)spare0; (void)spare1; (void)spare2; (void)spare3;
    (void)Kpk_lo; (void)Vt_lo;

    // k-split partials alias the spare region (nothing else touches it):
    // Opart 32*2048*32*4 = 8.39 MB, Oml 0.52 MB
    float* Opart = (float*)d_ws;
    float* Oml   = (float*)((char*)d_ws + 8388608);

    conv_w<<<dim3(12, 4, 6), 256, 0, stream>>>(Wq_aa, Wk_aa, Wv_a, Wk_ab, Wq_bb, Wo,
                                               W5t_hi, W5t_lo, Wot_hi, Wot_lo);
    proj_fused<<<dim3(640), 256, 0, stream>>>(A, B, W5t_hi,
                                              bq_aa, bk_aa, bv_a, bk_ab, bq_bb,
                                              Qpk_hi, Qpk_lo, Kpk_hi, Vt_hi);
    attn_mfma8<<<dim3(1024), 256, 0, stream>>>(Qpk_hi, Qpk_lo, Kpk_hi, Vt_hi,
                                               Opart, Oml);
    attn_merge<<<dim3(64, 8, 2), 256, 0, stream>>>(Opart, Oml, Cx_hi, Cx_lo);
    gemm_out_mfma2<<<dim3(4, 128), 256, 0, stream>>>(Cx_hi, Cx_lo, Wot_hi, Wot_lo,
                                                     bo, out);
}